// Round 1
// baseline (5709.474 us; speedup 1.0000x reference)
//
#include <hip/hip_runtime.h>
#include <math.h>

// Problem constants
#define BB 16
#define NN 8192
#define SS 1024
#define GG 32
#define MTOT (BB*SS*GG)   // 524288
// MLP: 6 -> 64 -> 64 -> 128

// ---------------------------------------------------------------------------
// Kernel 1: farthest point sampling. One block per batch, 1024 threads.
// Each thread owns 8 points (p = k*1024 + t) with coords + running min-dist in
// registers. Exact f32 semantics (no FMA contraction) to match numpy/jax.
// Tie-break: argmax picks the LOWEST index among equal dists (key packing).
// ---------------------------------------------------------------------------
__global__ __launch_bounds__(1024) void fps_kernel(const float* __restrict__ xyz,
                                                   float* __restrict__ newxyz)
{
    const int b = blockIdx.x;
    const int t = threadIdx.x;
    const float* base = xyz + (size_t)b * NN * 3;

    float px[8], py[8], pz[8], dd[8];
#pragma unroll
    for (int k = 0; k < 8; ++k) {
        const int p = (k << 10) + t;
        px[k] = base[p * 3 + 0];
        py[k] = base[p * 3 + 1];
        pz[k] = base[p * 3 + 2];
        dd[k] = 1e10f;
    }

    __shared__ float cb[3];
    __shared__ unsigned long long slots[16];
    const int wave = t >> 6;
    const int lane = t & 63;

    int far = 0;
    float* outb = newxyz + (size_t)b * SS * 3;

    for (int s = 0; s < SS; ++s) {
        // owner of current farthest point publishes centroid + writes output
        if ((far & 1023) == t) {
            const int k = far >> 10;
            cb[0] = px[k]; cb[1] = py[k]; cb[2] = pz[k];
            outb[s * 3 + 0] = px[k];
            outb[s * 3 + 1] = py[k];
            outb[s * 3 + 2] = pz[k];
        }
        __syncthreads();   // sync A
        const float cx = cb[0], cy = cb[1], cz = cb[2];

        unsigned long long best = 0ull;
#pragma unroll
        for (int k = 0; k < 8; ++k) {
            const float dx = __fsub_rn(px[k], cx);
            const float dy = __fsub_rn(py[k], cy);
            const float dz = __fsub_rn(pz[k], cz);
            const float d  = __fadd_rn(__fadd_rn(__fmul_rn(dx, dx), __fmul_rn(dy, dy)),
                                       __fmul_rn(dz, dz));
            const float nd = fminf(dd[k], d);
            dd[k] = nd;
            const unsigned long long key =
                ((unsigned long long)__float_as_uint(nd) << 32) |
                (unsigned long long)(0xFFFFFFFFu - (unsigned)((k << 10) + t));
            best = (key > best) ? key : best;
        }
        // wave butterfly max
#pragma unroll
        for (int off = 32; off > 0; off >>= 1) {
            const unsigned long long o = __shfl_xor(best, off);
            best = (o > best) ? o : best;
        }
        if (lane == 0) slots[wave] = best;
        __syncthreads();   // sync B
        unsigned long long gbest = slots[0];
#pragma unroll
        for (int w = 1; w < 16; ++w) {
            const unsigned long long o = slots[w];
            gbest = (o > gbest) ? o : gbest;
        }
        far = (int)(0xFFFFFFFFu - (unsigned)(gbest & 0xFFFFFFFFull));
    }
}

// ---------------------------------------------------------------------------
// Kernel 2: ball query + gather. One wave per centroid. Scans points in index
// order, takes first 32 with sq <= r^2 (exact f32 compare), pads with first.
// Writes grouped features SoA: v[ch][m], ch 0..2 = rel xyz, 3..5 = features.
// ---------------------------------------------------------------------------
__global__ __launch_bounds__(256) void ball_gather_kernel(const float* __restrict__ xyz,
                                                          const float* __restrict__ feat,
                                                          const float* __restrict__ newxyz,
                                                          float* __restrict__ v)
{
    const int wid  = (int)((blockIdx.x * 256 + threadIdx.x) >> 6);
    const int lane = threadIdx.x & 63;
    if (wid >= BB * SS) return;
    const int b = wid >> 10;

    const float cx = newxyz[wid * 3 + 0];
    const float cy = newxyz[wid * 3 + 1];
    const float cz = newxyz[wid * 3 + 2];
    const float* xb = xyz + (size_t)b * NN * 3;
    const float* fb = feat + (size_t)b * NN * 3;
    const size_t mbase = (size_t)wid * GG;

    int cnt = 0, firstp = -1;
    for (int base = 0; base < NN && cnt < GG; base += 64) {
        const int p = base + lane;
        const float x = xb[p * 3 + 0], y = xb[p * 3 + 1], z = xb[p * 3 + 2];
        const float dx = __fsub_rn(cx, x);
        const float dy = __fsub_rn(cy, y);
        const float dz = __fsub_rn(cz, z);
        const float d  = __fadd_rn(__fadd_rn(__fmul_rn(dx, dx), __fmul_rn(dy, dy)),
                                   __fmul_rn(dz, dz));
        const bool hit = (d <= 0.04f);
        const unsigned long long m = __ballot(hit);
        if (firstp < 0 && m != 0ull) firstp = base + (int)__builtin_ctzll(m);
        const int pos = cnt + (int)__popcll(m & ((1ull << lane) - 1ull));
        if (hit && pos < GG) {
            const size_t mm = mbase + pos;
            v[0 * (size_t)MTOT + mm] = __fsub_rn(x, cx);
            v[1 * (size_t)MTOT + mm] = __fsub_rn(y, cy);
            v[2 * (size_t)MTOT + mm] = __fsub_rn(z, cz);
            v[3 * (size_t)MTOT + mm] = fb[p * 3 + 0];
            v[4 * (size_t)MTOT + mm] = fb[p * 3 + 1];
            v[5 * (size_t)MTOT + mm] = fb[p * 3 + 2];
        }
        cnt += (int)__popcll(m);
    }
    if (cnt < GG) {
        const int p = firstp;
        const float x = xb[p * 3 + 0], y = xb[p * 3 + 1], z = xb[p * 3 + 2];
        const float gx = __fsub_rn(x, cx);
        const float gy = __fsub_rn(y, cy);
        const float gz = __fsub_rn(z, cz);
        const float f0 = fb[p * 3 + 0], f1 = fb[p * 3 + 1], f2 = fb[p * 3 + 2];
        for (int j = cnt + lane; j < GG; j += 64) {
            const size_t mm = mbase + j;
            v[0 * (size_t)MTOT + mm] = gx;
            v[1 * (size_t)MTOT + mm] = gy;
            v[2 * (size_t)MTOT + mm] = gz;
            v[3 * (size_t)MTOT + mm] = f0;
            v[4 * (size_t)MTOT + mm] = f1;
            v[5 * (size_t)MTOT + mm] = f2;
        }
    }
}

// ---------------------------------------------------------------------------
// Stats kernels (wave-cooperative: lane == output channel; contiguous point
// chunk per wave). Per-block partial sums -> ws; single-block f64 finalize.
// ---------------------------------------------------------------------------

// stats of x1 = W1 v + b1 (64 ch)
__global__ __launch_bounds__(256) void stats1_kernel(const float* __restrict__ v,
                                                     const float* __restrict__ w0,
                                                     const float* __restrict__ b0,
                                                     float* __restrict__ part)
{
    __shared__ float w1t[6][64];
    __shared__ float pS[4][64], pQ[4][64];
    const int tid = threadIdx.x;
    for (int i = tid; i < 384; i += 256) w1t[i % 6][i / 6] = w0[i];
    __syncthreads();

    const int lane = tid & 63;
    const int wvb  = tid >> 6;
    const int wv   = (int)((blockIdx.x * 256 + tid) >> 6);
    const int m0   = wv * 128;              // 4096 waves * 128 pts = MTOT
    const float bias = b0[lane];

    float s = 0.f, q = 0.f;
    for (int i = 0; i < 128; ++i) {
        const int m = m0 + i;
        float x = bias;
#pragma unroll
        for (int c = 0; c < 6; ++c) x = fmaf(w1t[c][lane], v[(size_t)c * MTOT + m], x);
        s += x; q = fmaf(x, x, q);
    }
    pS[wvb][lane] = s; pQ[wvb][lane] = q;
    __syncthreads();
    if (tid < 64) {
        part[blockIdx.x * 128 + tid]      = pS[0][tid] + pS[1][tid] + pS[2][tid] + pS[3][tid];
        part[blockIdx.x * 128 + 64 + tid] = pQ[0][tid] + pQ[1][tid] + pQ[2][tid] + pQ[3][tid];
    }
}

// finalize: A = g * rsqrt(var+eps); C = (b - mean)*A + beta
__global__ void finalize_kernel(int nch, int nblk,
                                const float* __restrict__ part,
                                const float* __restrict__ g,
                                const float* __restrict__ bias,
                                const float* __restrict__ beta,
                                float* __restrict__ A,
                                float* __restrict__ C)
{
    const int o = threadIdx.x;
    if (o >= nch) return;
    double s = 0.0, q = 0.0;
    for (int i = 0; i < nblk; ++i) {
        s += (double)part[i * 2 * nch + o];
        q += (double)part[i * 2 * nch + nch + o];
    }
    const double mean = s / (double)MTOT;
    double var = q / (double)MTOT - mean * mean;
    if (var < 0.0) var = 0.0;
    const double rs = 1.0 / sqrt(var + 1e-5);
    const double a  = (double)g[o] * rs;
    A[o] = (float)a;
    C[o] = (float)(((double)bias[o] - mean) * a + (double)beta[o]);
}

// stats of x2 = W2 h1 + b2 (64 ch); h1 = relu(A1*(W1 v) + C1)
__global__ __launch_bounds__(256) void stats2_kernel(const float* __restrict__ v,
                                                     const float* __restrict__ w0,
                                                     const float* __restrict__ w1,
                                                     const float* __restrict__ b1,
                                                     const float* __restrict__ par,
                                                     float* __restrict__ part)
{
    __shared__ float w1t[6][64];
    __shared__ float w2t[64][64];
    __shared__ float A1s[64], C1s[64];
    __shared__ float pS[4][64], pQ[4][64];
    const int tid = threadIdx.x;
    for (int i = tid; i < 384; i += 256)  w1t[i % 6][i / 6]   = w0[i];
    for (int i = tid; i < 4096; i += 256) w2t[i & 63][i >> 6] = w1[i];
    if (tid < 64) { A1s[tid] = par[tid]; C1s[tid] = par[64 + tid]; }
    __syncthreads();

    const int lane = tid & 63;
    const int wvb  = tid >> 6;
    const int wv   = (int)((blockIdx.x * 256 + tid) >> 6);
    const int m0   = wv * 128;
    const float bias2 = b1[lane];
    const float a1 = A1s[lane], c1 = C1s[lane];

    float s = 0.f, q = 0.f;
    for (int i = 0; i < 128; ++i) {
        const int m = m0 + i;
        float x = 0.f;
#pragma unroll
        for (int c = 0; c < 6; ++c) x = fmaf(w1t[c][lane], v[(size_t)c * MTOT + m], x);
        const float h1 = fmaxf(fmaf(a1, x, c1), 0.f);
        float e0 = bias2, e1 = 0.f;
#pragma unroll
        for (int c = 0; c < 64; c += 2) {
            e0 = fmaf(w2t[c][lane],     __shfl(h1, c),     e0);
            e1 = fmaf(w2t[c + 1][lane], __shfl(h1, c + 1), e1);
        }
        const float x2 = e0 + e1;
        s += x2; q = fmaf(x2, x2, q);
    }
    pS[wvb][lane] = s; pQ[wvb][lane] = q;
    __syncthreads();
    if (tid < 64) {
        part[blockIdx.x * 128 + tid]      = pS[0][tid] + pS[1][tid] + pS[2][tid] + pS[3][tid];
        part[blockIdx.x * 128 + 64 + tid] = pQ[0][tid] + pQ[1][tid] + pQ[2][tid] + pQ[3][tid];
    }
}

// stats of x3 = W3 h2 + b3 (128 ch); h2 = relu(A2*(W2 h1) + C2)
__global__ __launch_bounds__(256) void stats3_kernel(const float* __restrict__ v,
                                                     const float* __restrict__ w0,
                                                     const float* __restrict__ w1,
                                                     const float* __restrict__ w2m,
                                                     const float* __restrict__ b2,
                                                     const float* __restrict__ par,
                                                     float* __restrict__ part)
{
    __shared__ float w1t[6][64];
    __shared__ float w2t[64][64];
    __shared__ float w3t[64][128];
    __shared__ float A1s[64], C1s[64], A2s[64], C2s[64];
    __shared__ float pS[4][128], pQ[4][128];
    const int tid = threadIdx.x;
    for (int i = tid; i < 384; i += 256)  w1t[i % 6][i / 6]   = w0[i];
    for (int i = tid; i < 4096; i += 256) w2t[i & 63][i >> 6] = w1[i];
    for (int i = tid; i < 8192; i += 256) w3t[i & 63][i >> 6] = w2m[i];
    if (tid < 64) {
        A1s[tid] = par[tid];       C1s[tid] = par[64 + tid];
        A2s[tid] = par[128 + tid]; C2s[tid] = par[192 + tid];
    }
    __syncthreads();

    const int lane = tid & 63;
    const int wvb  = tid >> 6;
    const int wv   = (int)((blockIdx.x * 256 + tid) >> 6);
    const int m0   = wv * 128;
    const float a1 = A1s[lane], c1 = C1s[lane];
    const float a2 = A2s[lane], c2 = C2s[lane];
    const float b3a = b2[lane], b3b = b2[lane + 64];

    float s0 = 0.f, q0 = 0.f, s1 = 0.f, q1 = 0.f;
    for (int i = 0; i < 128; ++i) {
        const int m = m0 + i;
        float x = 0.f;
#pragma unroll
        for (int c = 0; c < 6; ++c) x = fmaf(w1t[c][lane], v[(size_t)c * MTOT + m], x);
        const float h1 = fmaxf(fmaf(a1, x, c1), 0.f);
        float e0 = 0.f, e1 = 0.f;
#pragma unroll
        for (int c = 0; c < 64; c += 2) {
            e0 = fmaf(w2t[c][lane],     __shfl(h1, c),     e0);
            e1 = fmaf(w2t[c + 1][lane], __shfl(h1, c + 1), e1);
        }
        const float h2 = fmaxf(fmaf(a2, e0 + e1, c2), 0.f);
        float f0 = b3a, f1 = 0.f, g0 = b3b, g1 = 0.f;
#pragma unroll
        for (int c = 0; c < 64; c += 2) {
            const float hA = __shfl(h2, c);
            const float hB = __shfl(h2, c + 1);
            f0 = fmaf(w3t[c][lane],          hA, f0);
            f1 = fmaf(w3t[c + 1][lane],      hB, f1);
            g0 = fmaf(w3t[c][lane + 64],     hA, g0);
            g1 = fmaf(w3t[c + 1][lane + 64], hB, g1);
        }
        const float x3a = f0 + f1, x3b = g0 + g1;
        s0 += x3a; q0 = fmaf(x3a, x3a, q0);
        s1 += x3b; q1 = fmaf(x3b, x3b, q1);
    }
    pS[wvb][lane] = s0; pS[wvb][lane + 64] = s1;
    pQ[wvb][lane] = q0; pQ[wvb][lane + 64] = q1;
    __syncthreads();
    if (tid < 128) {
        part[blockIdx.x * 256 + tid]       = pS[0][tid] + pS[1][tid] + pS[2][tid] + pS[3][tid];
        part[blockIdx.x * 256 + 128 + tid] = pQ[0][tid] + pQ[1][tid] + pQ[2][tid] + pQ[3][tid];
    }
}

// final: full chain + BN3 + relu + max over group (32 pts) -> output rows
__global__ __launch_bounds__(256) void final_kernel(const float* __restrict__ v,
                                                    const float* __restrict__ w0,
                                                    const float* __restrict__ w1,
                                                    const float* __restrict__ w2m,
                                                    const float* __restrict__ par,
                                                    float* __restrict__ outF)
{
    __shared__ float w1t[6][64];
    __shared__ float w2t[64][64];
    __shared__ float w3t[64][128];
    __shared__ float A1s[64], C1s[64], A2s[64], C2s[64], A3s[128], C3s[128];
    const int tid = threadIdx.x;
    for (int i = tid; i < 384; i += 256)  w1t[i % 6][i / 6]   = w0[i];
    for (int i = tid; i < 4096; i += 256) w2t[i & 63][i >> 6] = w1[i];
    for (int i = tid; i < 8192; i += 256) w3t[i & 63][i >> 6] = w2m[i];
    if (tid < 64) {
        A1s[tid] = par[tid];       C1s[tid] = par[64 + tid];
        A2s[tid] = par[128 + tid]; C2s[tid] = par[192 + tid];
    }
    if (tid < 128) {
        A3s[tid] = par[256 + tid]; C3s[tid] = par[384 + tid];
    }
    __syncthreads();

    const int lane = tid & 63;
    const int wv   = (int)((blockIdx.x * 256 + tid) >> 6);
    const float a1 = A1s[lane], c1 = C1s[lane];
    const float a2 = A2s[lane], c2 = C2s[lane];
    const float a3a = A3s[lane], c3a = C3s[lane];
    const float a3b = A3s[lane + 64], c3b = C3s[lane + 64];

    const int grp0 = wv * 4;   // 4096 waves * 4 groups = 16384
    for (int gi = 0; gi < 4; ++gi) {
        const int grp = grp0 + gi;
        const size_t pbase = (size_t)grp * GG;
        float mx0 = 0.f, mx1 = 0.f;   // relu outputs are >= 0
        for (int i = 0; i < GG; ++i) {
            const size_t m = pbase + i;
            float x = 0.f;
#pragma unroll
            for (int c = 0; c < 6; ++c) x = fmaf(w1t[c][lane], v[(size_t)c * MTOT + m], x);
            const float h1 = fmaxf(fmaf(a1, x, c1), 0.f);
            float e0 = 0.f, e1 = 0.f;
#pragma unroll
            for (int c = 0; c < 64; c += 2) {
                e0 = fmaf(w2t[c][lane],     __shfl(h1, c),     e0);
                e1 = fmaf(w2t[c + 1][lane], __shfl(h1, c + 1), e1);
            }
            const float h2 = fmaxf(fmaf(a2, e0 + e1, c2), 0.f);
            float f0 = 0.f, f1 = 0.f, g0 = 0.f, g1 = 0.f;
#pragma unroll
            for (int c = 0; c < 64; c += 2) {
                const float hA = __shfl(h2, c);
                const float hB = __shfl(h2, c + 1);
                f0 = fmaf(w3t[c][lane],          hA, f0);
                f1 = fmaf(w3t[c + 1][lane],      hB, f1);
                g0 = fmaf(w3t[c][lane + 64],     hA, g0);
                g1 = fmaf(w3t[c + 1][lane + 64], hB, g1);
            }
            const float h3a = fmaxf(fmaf(a3a, f0 + f1, c3a), 0.f);
            const float h3b = fmaxf(fmaf(a3b, g0 + g1, c3b), 0.f);
            mx0 = fmaxf(mx0, h3a);
            mx1 = fmaxf(mx1, h3b);
        }
        outF[(size_t)grp * 128 + lane]      = mx0;
        outF[(size_t)grp * 128 + 64 + lane] = mx1;
    }
}

// ---------------------------------------------------------------------------
extern "C" void kernel_launch(void* const* d_in, const int* in_sizes, int n_in,
                              void* d_out, int out_size, void* d_ws, size_t ws_size,
                              hipStream_t stream)
{
    const float* xyz  = (const float*)d_in[0];
    const float* feat = (const float*)d_in[1];
    const float* w0  = (const float*)d_in[2];
    const float* b0  = (const float*)d_in[3];
    const float* g0  = (const float*)d_in[4];
    const float* bt0 = (const float*)d_in[5];
    const float* w1  = (const float*)d_in[6];
    const float* b1  = (const float*)d_in[7];
    const float* g1  = (const float*)d_in[8];
    const float* bt1 = (const float*)d_in[9];
    const float* w2  = (const float*)d_in[10];
    const float* b2  = (const float*)d_in[11];
    const float* g2  = (const float*)d_in[12];
    const float* bt2 = (const float*)d_in[13];

    float* out    = (float*)d_out;
    float* newxyz = out;                 // (16,1024,3)
    float* outF   = out + BB * SS * 3;   // (16,1024,128)

    float* wsf   = (float*)d_ws;
    float* v     = wsf;                         // 6*MTOT floats
    float* part1 = wsf + 6ull * MTOT;           // 1024*128
    float* part2 = part1 + 1024 * 128;          // 1024*128
    float* part3 = part2 + 1024 * 128;          // 1024*256
    float* par   = part3 + 1024 * 256;          // 512 floats: A1,C1,A2,C2,A3,C3

    fps_kernel<<<dim3(BB), dim3(1024), 0, stream>>>(xyz, newxyz);
    ball_gather_kernel<<<dim3(4096), dim3(256), 0, stream>>>(xyz, feat, newxyz, v);

    stats1_kernel<<<dim3(1024), dim3(256), 0, stream>>>(v, w0, b0, part1);
    finalize_kernel<<<dim3(1), dim3(128), 0, stream>>>(64, 1024, part1, g0, b0, bt0,
                                                       par + 0, par + 64);
    stats2_kernel<<<dim3(1024), dim3(256), 0, stream>>>(v, w0, w1, b1, par, part2);
    finalize_kernel<<<dim3(1), dim3(128), 0, stream>>>(64, 1024, part2, g1, b1, bt1,
                                                       par + 128, par + 192);
    stats3_kernel<<<dim3(1024), dim3(256), 0, stream>>>(v, w0, w1, w2, b2, par, part3);
    finalize_kernel<<<dim3(1), dim3(128), 0, stream>>>(128, 1024, part3, g2, b2, bt2,
                                                       par + 256, par + 384);
    final_kernel<<<dim3(1024), dim3(256), 0, stream>>>(v, w0, w1, w2, par, outF);
}

// Round 2
// 2631.506 us; speedup vs baseline: 2.1697x; 2.1697x over previous
//
#include <hip/hip_runtime.h>
#include <math.h>

// Problem constants
#define BB 16
#define NN 8192
#define SS 1024
#define GG 32
#define MTOT (BB*SS*GG)   // 524288
// MLP: 6 -> 64 -> 64 -> 128

struct alignas(16) f4 { float v[4]; };

// ---------------------------------------------------------------------------
// Kernel 1: farthest point sampling. One block per batch, 256 threads, 32
// points per thread in registers. All coords also staged in LDS so every
// thread can read the centroid directly -> ONE barrier per step (double-
// buffered reduction slots remove the WAR barrier).
// Exact f32 semantics (no FMA contraction) to match numpy/jax; argmax ties
// break to the LOWEST index via key packing.
// ---------------------------------------------------------------------------
__global__ __launch_bounds__(256) void fps_kernel(const float* __restrict__ xyz,
                                                  float* __restrict__ newxyz)
{
    __shared__ float lx[NN], ly[NN], lz[NN];            // 96 KB
    __shared__ unsigned long long slots[2][4];
    const int b = blockIdx.x;
    const int t = threadIdx.x;
    const int wave = t >> 6, lane = t & 63;
    const float* base = xyz + (size_t)b * NN * 3;

    float px[32], py[32], pz[32], dd[32];
#pragma unroll
    for (int k = 0; k < 32; ++k) {
        const int p = (k << 8) + t;
        const float x = base[p * 3 + 0];
        const float y = base[p * 3 + 1];
        const float z = base[p * 3 + 2];
        px[k] = x; py[k] = y; pz[k] = z; dd[k] = 1e10f;
        lx[p] = x; ly[p] = y; lz[p] = z;
    }
    __syncthreads();

    int far = 0;
    float* outb = newxyz + (size_t)b * SS * 3;
    for (int s = 0; s < SS; ++s) {
        const float cx = lx[far], cy = ly[far], cz = lz[far];
        if (t == 0) {
            outb[s * 3 + 0] = cx;
            outb[s * 3 + 1] = cy;
            outb[s * 3 + 2] = cz;
        }
        unsigned long long best = 0ull;
#pragma unroll
        for (int k = 0; k < 32; ++k) {
            const float dx = __fsub_rn(px[k], cx);
            const float dy = __fsub_rn(py[k], cy);
            const float dz = __fsub_rn(pz[k], cz);
            const float d  = __fadd_rn(__fadd_rn(__fmul_rn(dx, dx), __fmul_rn(dy, dy)),
                                       __fmul_rn(dz, dz));
            const float nd = fminf(dd[k], d);
            dd[k] = nd;
            const unsigned long long key =
                ((unsigned long long)__float_as_uint(nd) << 32) |
                (unsigned long long)(0xFFFFFFFFu - (unsigned)((k << 8) + t));
            best = (key > best) ? key : best;
        }
#pragma unroll
        for (int off = 32; off > 0; off >>= 1) {
            const unsigned long long o = __shfl_xor(best, off);
            best = (o > best) ? o : best;
        }
        if (lane == 0) slots[s & 1][wave] = best;
        __syncthreads();
        unsigned long long g = slots[s & 1][0];
#pragma unroll
        for (int w = 1; w < 4; ++w) {
            const unsigned long long o = slots[s & 1][w];
            g = (o > g) ? o : g;
        }
        far = (int)(0xFFFFFFFFu - (unsigned)(g & 0xFFFFFFFFull));
    }
}

// ---------------------------------------------------------------------------
// Kernel 2: ball query + gather (unchanged from round 1; not a hot spot).
// ---------------------------------------------------------------------------
__global__ __launch_bounds__(256) void ball_gather_kernel(const float* __restrict__ xyz,
                                                          const float* __restrict__ feat,
                                                          const float* __restrict__ newxyz,
                                                          float* __restrict__ v)
{
    const int wid  = (int)((blockIdx.x * 256 + threadIdx.x) >> 6);
    const int lane = threadIdx.x & 63;
    if (wid >= BB * SS) return;
    const int b = wid >> 10;

    const float cx = newxyz[wid * 3 + 0];
    const float cy = newxyz[wid * 3 + 1];
    const float cz = newxyz[wid * 3 + 2];
    const float* xb = xyz + (size_t)b * NN * 3;
    const float* fb = feat + (size_t)b * NN * 3;
    const size_t mbase = (size_t)wid * GG;

    int cnt = 0, firstp = -1;
    for (int base = 0; base < NN && cnt < GG; base += 64) {
        const int p = base + lane;
        const float x = xb[p * 3 + 0], y = xb[p * 3 + 1], z = xb[p * 3 + 2];
        const float dx = __fsub_rn(cx, x);
        const float dy = __fsub_rn(cy, y);
        const float dz = __fsub_rn(cz, z);
        const float d  = __fadd_rn(__fadd_rn(__fmul_rn(dx, dx), __fmul_rn(dy, dy)),
                                   __fmul_rn(dz, dz));
        const bool hit = (d <= 0.04f);
        const unsigned long long m = __ballot(hit);
        if (firstp < 0 && m != 0ull) firstp = base + (int)__builtin_ctzll(m);
        const int pos = cnt + (int)__popcll(m & ((1ull << lane) - 1ull));
        if (hit && pos < GG) {
            const size_t mm = mbase + pos;
            v[0 * (size_t)MTOT + mm] = __fsub_rn(x, cx);
            v[1 * (size_t)MTOT + mm] = __fsub_rn(y, cy);
            v[2 * (size_t)MTOT + mm] = __fsub_rn(z, cz);
            v[3 * (size_t)MTOT + mm] = fb[p * 3 + 0];
            v[4 * (size_t)MTOT + mm] = fb[p * 3 + 1];
            v[5 * (size_t)MTOT + mm] = fb[p * 3 + 2];
        }
        cnt += (int)__popcll(m);
    }
    if (cnt < GG) {
        const int p = firstp;
        const float x = xb[p * 3 + 0], y = xb[p * 3 + 1], z = xb[p * 3 + 2];
        const float gx = __fsub_rn(x, cx);
        const float gy = __fsub_rn(y, cy);
        const float gz = __fsub_rn(z, cz);
        const float f0 = fb[p * 3 + 0], f1 = fb[p * 3 + 1], f2 = fb[p * 3 + 2];
        for (int j = cnt + lane; j < GG; j += 64) {
            const size_t mm = mbase + j;
            v[0 * (size_t)MTOT + mm] = gx;
            v[1 * (size_t)MTOT + mm] = gy;
            v[2 * (size_t)MTOT + mm] = gz;
            v[3 * (size_t)MTOT + mm] = f0;
            v[4 * (size_t)MTOT + mm] = f1;
            v[5 * (size_t)MTOT + mm] = f2;
        }
    }
}

// ---------------------------------------------------------------------------
// Tiled MLP chain. 512 threads, TILE=128 points per tile, tpb tiles/block.
// Thread micro-tiles: L1/L2 -> 4ch x 4pt, L3 -> 8ch x 4pt. Operands staged
// in LDS, f4 (b128) reads, register accumulators. BN stats via lane
// butterfly over the 32 point-tiles -> per-tile partials in `part`.
// PHASE: 1 = stats of x1; 2 = stats of x2; 3 = stats of x3; 4 = final
// (BN3 + relu + group max -> outF).
// ---------------------------------------------------------------------------
template<int PHASE>
__global__ __launch_bounds__(512) void mlp_kernel(
    const float* __restrict__ v,
    const float* __restrict__ w0g, const float* __restrict__ b0g,
    const float* __restrict__ w1g, const float* __restrict__ b1g,
    const float* __restrict__ w2g, const float* __restrict__ b2g,
    const float* __restrict__ par,
    float* __restrict__ part,
    float* __restrict__ outF,
    int tpb)
{
    constexpr int TILE = 128;
    __shared__ float w1t[6][64];                       // w1t[k][ch]
    __shared__ float w2t[(PHASE >= 2) ? 64 : 1][64];   // w2t[k][ch]
    __shared__ float w3t[(PHASE >= 3) ? 64 : 1][128];  // w3t[k][ch]
    __shared__ float vt[6][TILE];
    __shared__ float h1s[(PHASE >= 2) ? 64 : 1][TILE];
    __shared__ float h2s[(PHASE >= 3) ? 64 : 1][TILE];

    const int tid = threadIdx.x;
    const int ptt = tid & 31;        // point-tile (4 pts each)
    const int cht = tid >> 5;        // ch-tile 0..15
    const int p0  = ptt * 4;
    const int c4  = cht * 4;
    const int c8  = cht * 8;

    for (int i = tid; i < 384; i += 512) w1t[i % 6][i / 6] = w0g[i];
    if constexpr (PHASE >= 2) {
        for (int i = tid; i < 4096; i += 512) w2t[i & 63][i >> 6] = w1g[i];
    }
    if constexpr (PHASE >= 3) {
        for (int i = tid; i < 8192; i += 512) w3t[i & 63][i >> 6] = w2g[i];
    }

    float a1v[4], c1v[4], a2v[4], c2v[4], a3v[8], c3v[8];
    float bias1[4], bias2[4], bias3[8];
    if constexpr (PHASE == 1) {
#pragma unroll
        for (int ci = 0; ci < 4; ++ci) bias1[ci] = b0g[c4 + ci];
    }
    if constexpr (PHASE >= 2) {
#pragma unroll
        for (int ci = 0; ci < 4; ++ci) { a1v[ci] = par[c4 + ci]; c1v[ci] = par[64 + c4 + ci]; }
    }
    if constexpr (PHASE == 2) {
#pragma unroll
        for (int ci = 0; ci < 4; ++ci) bias2[ci] = b1g[c4 + ci];
    }
    if constexpr (PHASE >= 3) {
#pragma unroll
        for (int ci = 0; ci < 4; ++ci) { a2v[ci] = par[128 + c4 + ci]; c2v[ci] = par[192 + c4 + ci]; }
    }
    if constexpr (PHASE == 3) {
#pragma unroll
        for (int ci = 0; ci < 8; ++ci) bias3[ci] = b2g[c8 + ci];
    }
    if constexpr (PHASE == 4) {
#pragma unroll
        for (int ci = 0; ci < 8; ++ci) { a3v[ci] = par[256 + c8 + ci]; c3v[ci] = par[384 + c8 + ci]; }
    }

    for (int ti = 0; ti < tpb; ++ti) {
        const int tile = blockIdx.x * tpb + ti;
        const int m0 = tile * TILE;
        __syncthreads();   // protect LDS reuse from previous tile
        for (int i = tid; i < 6 * TILE; i += 512)
            vt[i >> 7][i & 127] = v[(size_t)(i >> 7) * MTOT + m0 + (i & 127)];
        __syncthreads();

        // ---- L1: x1_nb = W1 v ----
        f4 acc1[4];
#pragma unroll
        for (int ci = 0; ci < 4; ++ci) acc1[ci] = f4{0.f, 0.f, 0.f, 0.f};
#pragma unroll
        for (int k = 0; k < 6; ++k) {
            const f4 hv = *reinterpret_cast<const f4*>(&vt[k][p0]);
            const f4 wv = *reinterpret_cast<const f4*>(&w1t[k][c4]);
#pragma unroll
            for (int ci = 0; ci < 4; ++ci)
#pragma unroll
                for (int pj = 0; pj < 4; ++pj)
                    acc1[ci].v[pj] = fmaf(wv.v[ci], hv.v[pj], acc1[ci].v[pj]);
        }

        if constexpr (PHASE == 1) {
            float sv[4], qv[4];
#pragma unroll
            for (int ci = 0; ci < 4; ++ci) {
                float s = 0.f, q = 0.f;
#pragma unroll
                for (int pj = 0; pj < 4; ++pj) {
                    const float x = acc1[ci].v[pj] + bias1[ci];
                    s += x; q = fmaf(x, x, q);
                }
                sv[ci] = s; qv[ci] = q;
            }
#pragma unroll
            for (int off = 1; off < 32; off <<= 1) {
#pragma unroll
                for (int ci = 0; ci < 4; ++ci) {
                    sv[ci] += __shfl_xor(sv[ci], off);
                    qv[ci] += __shfl_xor(qv[ci], off);
                }
            }
            if (ptt == 0) {
#pragma unroll
                for (int ci = 0; ci < 4; ++ci) {
                    part[(size_t)tile * 128 + c4 + ci]      = sv[ci];
                    part[(size_t)tile * 128 + 64 + c4 + ci] = qv[ci];
                }
            }
            continue;
        } else {
            // h1 = relu(A1*x1_nb + C1)
#pragma unroll
            for (int ci = 0; ci < 4; ++ci) {
                f4 h;
#pragma unroll
                for (int pj = 0; pj < 4; ++pj)
                    h.v[pj] = fmaxf(fmaf(a1v[ci], acc1[ci].v[pj], c1v[ci]), 0.f);
                *reinterpret_cast<f4*>(&h1s[c4 + ci][p0]) = h;
            }
            __syncthreads();

            // ---- L2: x2_nb = W2 h1 ----
            f4 acc2[4];
#pragma unroll
            for (int ci = 0; ci < 4; ++ci) acc2[ci] = f4{0.f, 0.f, 0.f, 0.f};
#pragma unroll 4
            for (int k = 0; k < 64; ++k) {
                const f4 hv = *reinterpret_cast<const f4*>(&h1s[k][p0]);
                const f4 wv = *reinterpret_cast<const f4*>(&w2t[k][c4]);
#pragma unroll
                for (int ci = 0; ci < 4; ++ci)
#pragma unroll
                    for (int pj = 0; pj < 4; ++pj)
                        acc2[ci].v[pj] = fmaf(wv.v[ci], hv.v[pj], acc2[ci].v[pj]);
            }

            if constexpr (PHASE == 2) {
                float sv[4], qv[4];
#pragma unroll
                for (int ci = 0; ci < 4; ++ci) {
                    float s = 0.f, q = 0.f;
#pragma unroll
                    for (int pj = 0; pj < 4; ++pj) {
                        const float x = acc2[ci].v[pj] + bias2[ci];
                        s += x; q = fmaf(x, x, q);
                    }
                    sv[ci] = s; qv[ci] = q;
                }
#pragma unroll
                for (int off = 1; off < 32; off <<= 1) {
#pragma unroll
                    for (int ci = 0; ci < 4; ++ci) {
                        sv[ci] += __shfl_xor(sv[ci], off);
                        qv[ci] += __shfl_xor(qv[ci], off);
                    }
                }
                if (ptt == 0) {
#pragma unroll
                    for (int ci = 0; ci < 4; ++ci) {
                        part[(size_t)tile * 128 + c4 + ci]      = sv[ci];
                        part[(size_t)tile * 128 + 64 + c4 + ci] = qv[ci];
                    }
                }
                continue;
            } else {
                // h2 = relu(A2*x2_nb + C2)
#pragma unroll
                for (int ci = 0; ci < 4; ++ci) {
                    f4 h;
#pragma unroll
                    for (int pj = 0; pj < 4; ++pj)
                        h.v[pj] = fmaxf(fmaf(a2v[ci], acc2[ci].v[pj], c2v[ci]), 0.f);
                    *reinterpret_cast<f4*>(&h2s[c4 + ci][p0]) = h;
                }
                __syncthreads();

                // ---- L3: x3_nb = W3 h2 (8ch x 4pt) ----
                f4 acc3[8];
#pragma unroll
                for (int ci = 0; ci < 8; ++ci) acc3[ci] = f4{0.f, 0.f, 0.f, 0.f};
#pragma unroll 4
                for (int k = 0; k < 64; ++k) {
                    const f4 hv = *reinterpret_cast<const f4*>(&h2s[k][p0]);
                    const f4 wa = *reinterpret_cast<const f4*>(&w3t[k][c8]);
                    const f4 wb = *reinterpret_cast<const f4*>(&w3t[k][c8 + 4]);
#pragma unroll
                    for (int ci = 0; ci < 4; ++ci)
#pragma unroll
                        for (int pj = 0; pj < 4; ++pj) {
                            acc3[ci].v[pj]     = fmaf(wa.v[ci], hv.v[pj], acc3[ci].v[pj]);
                            acc3[ci + 4].v[pj] = fmaf(wb.v[ci], hv.v[pj], acc3[ci + 4].v[pj]);
                        }
                }

                if constexpr (PHASE == 3) {
                    float sv[8], qv[8];
#pragma unroll
                    for (int ci = 0; ci < 8; ++ci) {
                        float s = 0.f, q = 0.f;
#pragma unroll
                        for (int pj = 0; pj < 4; ++pj) {
                            const float x = acc3[ci].v[pj] + bias3[ci];
                            s += x; q = fmaf(x, x, q);
                        }
                        sv[ci] = s; qv[ci] = q;
                    }
#pragma unroll
                    for (int off = 1; off < 32; off <<= 1) {
#pragma unroll
                        for (int ci = 0; ci < 8; ++ci) {
                            sv[ci] += __shfl_xor(sv[ci], off);
                            qv[ci] += __shfl_xor(qv[ci], off);
                        }
                    }
                    if (ptt == 0) {
#pragma unroll
                        for (int ci = 0; ci < 8; ++ci) {
                            part[(size_t)tile * 256 + c8 + ci]       = sv[ci];
                            part[(size_t)tile * 256 + 128 + c8 + ci] = qv[ci];
                        }
                    }
                    continue;
                } else {
                    // ---- FINAL: y = relu(A3*x3_nb + C3); max over 32-pt group ----
                    float mx[8];
#pragma unroll
                    for (int ci = 0; ci < 8; ++ci) {
                        float m = 0.f;   // relu outputs >= 0
#pragma unroll
                        for (int pj = 0; pj < 4; ++pj) {
                            const float y = fmaxf(fmaf(a3v[ci], acc3[ci].v[pj], c3v[ci]), 0.f);
                            m = fmaxf(m, y);
                        }
                        mx[ci] = m;
                    }
#pragma unroll
                    for (int off = 1; off < 8; off <<= 1) {
#pragma unroll
                        for (int ci = 0; ci < 8; ++ci)
                            mx[ci] = fmaxf(mx[ci], __shfl_xor(mx[ci], off));
                    }
                    if ((ptt & 7) == 0) {
                        const int grp = tile * 4 + (ptt >> 3);
#pragma unroll
                        for (int ci = 0; ci < 8; ++ci)
                            outF[(size_t)grp * 128 + c8 + ci] = mx[ci];
                    }
                }
            }
        }
    }
}

// ---------------------------------------------------------------------------
// finalize: A = g * rsqrt(var+eps); C = (b - mean)*A + beta. 256 threads,
// R = 256/nch reducers per channel over nblk tile-partials, f64 accumulate.
// ---------------------------------------------------------------------------
__global__ __launch_bounds__(256) void finalize_kernel(int nch, int nblk,
                                                       const float* __restrict__ part,
                                                       const float* __restrict__ g,
                                                       const float* __restrict__ bias,
                                                       const float* __restrict__ beta,
                                                       float* __restrict__ A,
                                                       float* __restrict__ C)
{
    __shared__ double sd[256], qd[256];
    const int R = 256 / nch;
    const int o = (int)threadIdx.x % nch;
    const int r = (int)threadIdx.x / nch;
    double s = 0.0, q = 0.0;
    for (int i = r; i < nblk; i += R) {
        s += (double)part[(size_t)i * 2 * nch + o];
        q += (double)part[(size_t)i * 2 * nch + nch + o];
    }
    sd[threadIdx.x] = s; qd[threadIdx.x] = q;
    __syncthreads();
    if ((int)threadIdx.x < nch) {
        for (int j = 1; j < R; ++j) { s += sd[o + j * nch]; q += qd[o + j * nch]; }
        const double mean = s / (double)MTOT;
        double var = q / (double)MTOT - mean * mean;
        if (var < 0.0) var = 0.0;
        const double rs = 1.0 / sqrt(var + 1e-5);
        const double a  = (double)g[o] * rs;
        A[o] = (float)a;
        C[o] = (float)(((double)bias[o] - mean) * a + (double)beta[o]);
    }
}

// ---------------------------------------------------------------------------
extern "C" void kernel_launch(void* const* d_in, const int* in_sizes, int n_in,
                              void* d_out, int out_size, void* d_ws, size_t ws_size,
                              hipStream_t stream)
{
    const float* xyz  = (const float*)d_in[0];
    const float* feat = (const float*)d_in[1];
    const float* w0  = (const float*)d_in[2];
    const float* b0  = (const float*)d_in[3];
    const float* g0  = (const float*)d_in[4];
    const float* bt0 = (const float*)d_in[5];
    const float* w1  = (const float*)d_in[6];
    const float* b1  = (const float*)d_in[7];
    const float* g1  = (const float*)d_in[8];
    const float* bt1 = (const float*)d_in[9];
    const float* w2  = (const float*)d_in[10];
    const float* b2  = (const float*)d_in[11];
    const float* g2  = (const float*)d_in[12];
    const float* bt2 = (const float*)d_in[13];

    float* out    = (float*)d_out;
    float* newxyz = out;                 // (16,1024,3)
    float* outF   = out + BB * SS * 3;   // (16,1024,128)

    float* wsf  = (float*)d_ws;
    float* v    = wsf;                        // 6*MTOT floats (12.6 MB)
    float* part = wsf + 6ull * MTOT;          // 4096*256 floats (4 MB, reused per phase)
    float* par  = part + 4096 * 256;          // 512 floats: A1,C1,A2,C2,A3,C3

    fps_kernel<<<dim3(BB), dim3(256), 0, stream>>>(xyz, newxyz);
    ball_gather_kernel<<<dim3(4096), dim3(256), 0, stream>>>(xyz, feat, newxyz, v);

    mlp_kernel<1><<<dim3(2048), dim3(512), 0, stream>>>(v, w0, b0, w1, b1, w2, b2,
                                                        par, part, outF, 2);
    finalize_kernel<<<dim3(1), dim3(256), 0, stream>>>(64, 4096, part, g0, b0, bt0,
                                                       par + 0, par + 64);
    mlp_kernel<2><<<dim3(512), dim3(512), 0, stream>>>(v, w0, b0, w1, b1, w2, b2,
                                                       par, part, outF, 8);
    finalize_kernel<<<dim3(1), dim3(256), 0, stream>>>(64, 4096, part, g1, b1, bt1,
                                                       par + 128, par + 192);
    mlp_kernel<3><<<dim3(512), dim3(512), 0, stream>>>(v, w0, b0, w1, b1, w2, b2,
                                                       par, part, outF, 8);
    finalize_kernel<<<dim3(1), dim3(256), 0, stream>>>(128, 4096, part, g2, b2, bt2,
                                                       par + 256, par + 384);
    mlp_kernel<4><<<dim3(512), dim3(512), 0, stream>>>(v, w0, b0, w1, b1, w2, b2,
                                                       par, part, outF, 8);
}

// Round 3
// 2143.954 us; speedup vs baseline: 2.6631x; 1.2274x over previous
//
#include <hip/hip_runtime.h>
#include <math.h>

// Problem constants
#define BB 16
#define NN 8192
#define SS 1024
#define GG 32
#define MTOT (BB*SS*GG)   // 524288
// MLP: 6 -> 64 -> 64 -> 128

struct alignas(16) f4 { float v[4]; };

// ---------------------------------------------------------------------------
// prep: transpose raw weights: w2T[k][o] (64x64), w3T[k][o] (64x128)
// ---------------------------------------------------------------------------
__global__ __launch_bounds__(512) void prep_kernel(const float* __restrict__ w1g,
                                                   const float* __restrict__ w2g,
                                                   float* __restrict__ w2T,
                                                   float* __restrict__ w3T)
{
    const int tid = threadIdx.x;
    for (int i = tid; i < 4096; i += 512) w2T[(i & 63) * 64 + (i >> 6)] = w1g[i];
    for (int i = tid; i < 8192; i += 512) w3T[(i & 63) * 128 + (i >> 6)] = w2g[i];
}

// ---------------------------------------------------------------------------
// Kernel: farthest point sampling. One block per batch, 512 threads, 16 pts
// per thread in registers; all coords in LDS for centroid broadcast; ONE
// barrier per step. Exact f32 semantics (no FMA contraction); argmax ties ->
// lowest index (strict > within thread, key packing across lanes).
// ---------------------------------------------------------------------------
__global__ __launch_bounds__(512) void fps_kernel(const float* __restrict__ xyz,
                                                  float* __restrict__ newxyz)
{
    __shared__ float lx[NN], ly[NN], lz[NN];            // 96 KB
    __shared__ unsigned long long slots[2][8];
    const int b = blockIdx.x;
    const int t = threadIdx.x;
    const int wave = t >> 6, lane = t & 63;
    const float* base = xyz + (size_t)b * NN * 3;

    float px[16], py[16], pz[16], dd[16];
#pragma unroll
    for (int k = 0; k < 16; ++k) {
        const int p = (k << 9) + t;
        const float x = base[p * 3 + 0];
        const float y = base[p * 3 + 1];
        const float z = base[p * 3 + 2];
        px[k] = x; py[k] = y; pz[k] = z; dd[k] = 1e10f;
        lx[p] = x; ly[p] = y; lz[p] = z;
    }
    __syncthreads();

    int far = 0;
    float* outb = newxyz + (size_t)b * SS * 3;
    for (int s = 0; s < SS; ++s) {
        const float cx = lx[far], cy = ly[far], cz = lz[far];
        if (t == 0) {
            outb[s * 3 + 0] = cx;
            outb[s * 3 + 1] = cy;
            outb[s * 3 + 2] = cz;
        }
        float bf = -1.f;
        int   bi = 0;
#pragma unroll
        for (int k = 0; k < 16; ++k) {
            const float dx = __fsub_rn(px[k], cx);
            const float dy = __fsub_rn(py[k], cy);
            const float dz = __fsub_rn(pz[k], cz);
            const float d  = __fadd_rn(__fadd_rn(__fmul_rn(dx, dx), __fmul_rn(dy, dy)),
                                       __fmul_rn(dz, dz));
            const float nd = fminf(dd[k], d);
            dd[k] = nd;
            const bool c = nd > bf;
            bf = c ? nd : bf;
            bi = c ? ((k << 9) + t) : bi;
        }
        unsigned long long best =
            ((unsigned long long)__float_as_uint(bf) << 32) |
            (unsigned long long)(0xFFFFFFFFu - (unsigned)bi);
#pragma unroll
        for (int off = 32; off > 0; off >>= 1) {
            const unsigned long long o = __shfl_xor(best, off);
            best = (o > best) ? o : best;
        }
        if (lane == 0) slots[s & 1][wave] = best;
        __syncthreads();
        unsigned long long g = slots[s & 1][0];
#pragma unroll
        for (int w = 1; w < 8; ++w) {
            const unsigned long long o = slots[s & 1][w];
            g = (o > g) ? o : g;
        }
        far = (int)(0xFFFFFFFFu - (unsigned)(g & 0xFFFFFFFFull));
    }
}

// ---------------------------------------------------------------------------
// ball query + gather + v first/second moments (for analytic BN1 stats).
// One wave per centroid; first 32 hits in index order; pad with first hit.
// Each wave accumulates sum(v_c) and sum(v_c*v_d) over exactly the 32 slots
// it writes, then stores 42 floats to part1[wid*42+..].
// ---------------------------------------------------------------------------
__global__ __launch_bounds__(256) void ball_gather_kernel(const float* __restrict__ xyz,
                                                          const float* __restrict__ feat,
                                                          const float* __restrict__ newxyz,
                                                          float* __restrict__ v,
                                                          float* __restrict__ part1)
{
    const int wid  = (int)((blockIdx.x * 256 + threadIdx.x) >> 6);
    const int lane = threadIdx.x & 63;
    if (wid >= BB * SS) return;
    const int b = wid >> 10;

    const float cx = newxyz[wid * 3 + 0];
    const float cy = newxyz[wid * 3 + 1];
    const float cz = newxyz[wid * 3 + 2];
    const float* xb = xyz + (size_t)b * NN * 3;
    const float* fb = feat + (size_t)b * NN * 3;
    const size_t mbase = (size_t)wid * GG;

    float mS[6];
    float mP[36];
#pragma unroll
    for (int c = 0; c < 6; ++c) mS[c] = 0.f;
#pragma unroll
    for (int c = 0; c < 36; ++c) mP[c] = 0.f;

    int cnt = 0, firstp = -1;
    for (int base = 0; base < NN && cnt < GG; base += 64) {
        const int p = base + lane;
        const float x = xb[p * 3 + 0], y = xb[p * 3 + 1], z = xb[p * 3 + 2];
        const float dx = __fsub_rn(cx, x);
        const float dy = __fsub_rn(cy, y);
        const float dz = __fsub_rn(cz, z);
        const float d  = __fadd_rn(__fadd_rn(__fmul_rn(dx, dx), __fmul_rn(dy, dy)),
                                   __fmul_rn(dz, dz));
        const bool hit = (d <= 0.04f);
        const unsigned long long m = __ballot(hit);
        if (firstp < 0 && m != 0ull) firstp = base + (int)__builtin_ctzll(m);
        const int pos = cnt + (int)__popcll(m & ((1ull << lane) - 1ull));
        if (hit && pos < GG) {
            const size_t mm = mbase + pos;
            float a[6];
            a[0] = __fsub_rn(x, cx);
            a[1] = __fsub_rn(y, cy);
            a[2] = __fsub_rn(z, cz);
            a[3] = fb[p * 3 + 0];
            a[4] = fb[p * 3 + 1];
            a[5] = fb[p * 3 + 2];
#pragma unroll
            for (int c = 0; c < 6; ++c) {
                v[(size_t)c * MTOT + mm] = a[c];
                mS[c] += a[c];
#pragma unroll
                for (int dch = 0; dch < 6; ++dch)
                    mP[c * 6 + dch] = fmaf(a[c], a[dch], mP[c * 6 + dch]);
            }
        }
        cnt += (int)__popcll(m);
    }
    if (cnt < GG) {
        const int p = firstp;
        const float x = xb[p * 3 + 0], y = xb[p * 3 + 1], z = xb[p * 3 + 2];
        float a[6];
        a[0] = __fsub_rn(x, cx);
        a[1] = __fsub_rn(y, cy);
        a[2] = __fsub_rn(z, cz);
        a[3] = fb[p * 3 + 0];
        a[4] = fb[p * 3 + 1];
        a[5] = fb[p * 3 + 2];
        for (int j = cnt + lane; j < GG; j += 64) {
            const size_t mm = mbase + j;
#pragma unroll
            for (int c = 0; c < 6; ++c) {
                v[(size_t)c * MTOT + mm] = a[c];
                mS[c] += a[c];
#pragma unroll
                for (int dch = 0; dch < 6; ++dch)
                    mP[c * 6 + dch] = fmaf(a[c], a[dch], mP[c * 6 + dch]);
            }
        }
    }
    // wave-reduce the 42 moment values
#pragma unroll
    for (int off = 1; off < 64; off <<= 1) {
#pragma unroll
        for (int c = 0; c < 6; ++c) mS[c] += __shfl_xor(mS[c], off);
#pragma unroll
        for (int c = 0; c < 36; ++c) mP[c] += __shfl_xor(mP[c], off);
    }
    if (lane == 0) {
        float* row = part1 + (size_t)wid * 42;
#pragma unroll
        for (int c = 0; c < 6; ++c) row[c] = mS[c];
#pragma unroll
        for (int c = 0; c < 36; ++c) row[6 + c] = mP[c];
    }
}

// ---------------------------------------------------------------------------
// finalize1: reduce v moments (16384 x 42), compute analytic BN1 stats of
// x1 = W1 v (bias cancels in BN), write folded w1S[c][o] = A1[o]*w1[o][c]
// and c1[o] = beta1[o] - A1[o]*mean_nb[o].
// ---------------------------------------------------------------------------
__global__ __launch_bounds__(512) void finalize1_kernel(const float* __restrict__ part1,
                                                        const float* __restrict__ w0,
                                                        const float* __restrict__ g0,
                                                        const float* __restrict__ bt0,
                                                        float* __restrict__ w1S,
                                                        float* __restrict__ c1)
{
    __shared__ double red[504];
    __shared__ double tot[42];
    const int tid = threadIdx.x;
    if (tid < 504) {
        const int j = tid % 42, r = tid / 42;   // 12 reducers per channel
        double s = 0.0;
        for (int i = r; i < BB * SS; i += 12) s += (double)part1[(size_t)i * 42 + j];
        red[tid] = s;
    }
    __syncthreads();
    if (tid < 42) {
        double s = 0.0;
        for (int r = 0; r < 12; ++r) s += red[r * 42 + tid];
        tot[tid] = s / (double)MTOT;
    }
    __syncthreads();
    if (tid < 64) {
        double m1 = 0.0;
        for (int c = 0; c < 6; ++c) m1 += (double)w0[tid * 6 + c] * tot[c];
        double e2 = 0.0;
        for (int c = 0; c < 6; ++c)
            for (int d = 0; d < 6; ++d)
                e2 += (double)w0[tid * 6 + c] * (double)w0[tid * 6 + d] * tot[6 + c * 6 + d];
        double var = e2 - m1 * m1;
        if (var < 0.0) var = 0.0;
        const double A = (double)g0[tid] / sqrt(var + 1e-5);
        c1[tid] = (float)((double)bt0[tid] - A * m1);
        for (int c = 0; c < 6; ++c)
            w1S[c * 64 + tid] = (float)(A * (double)w0[tid * 6 + c]);
    }
}

// ---------------------------------------------------------------------------
// finalize2: reduce stats2 partials (512 blocks x [s256|q256]), compute
// A2/c2, write folded w2S = A2 o* w2T.
// ---------------------------------------------------------------------------
__global__ __launch_bounds__(512) void finalize2_kernel(const float* __restrict__ part,
                                                        const float* __restrict__ w2T,
                                                        const float* __restrict__ g1,
                                                        const float* __restrict__ bt1,
                                                        float* __restrict__ w2S,
                                                        float* __restrict__ c2)
{
    __shared__ double tot[512];
    __shared__ float As[64];
    const int tid = threadIdx.x;
    double s = 0.0;
    for (int blk = 0; blk < 512; ++blk) s += (double)part[(size_t)blk * 512 + tid];
    tot[tid] = s;
    __syncthreads();
    if (tid < 64) {
        double S = 0.0, Q = 0.0;
        for (int g = 0; g < 4; ++g) { S += tot[g * 64 + tid]; Q += tot[256 + g * 64 + tid]; }
        const double mean = S / (double)MTOT;
        double var = Q / (double)MTOT - mean * mean;
        if (var < 0.0) var = 0.0;
        const double A = (double)g1[tid] / sqrt(var + 1e-5);
        As[tid] = (float)A;
        c2[tid] = (float)((double)bt1[tid] - A * mean);
    }
    __syncthreads();
    for (int i = tid; i < 4096; i += 512) w2S[i] = As[i & 63] * w2T[i];
}

// ---------------------------------------------------------------------------
// finalize3: reduce stats3 partials (512 blocks x [s256|q256|s256|q256]),
// compute A3/c3, write folded w3S = A3 o* w3T.
// ---------------------------------------------------------------------------
__global__ __launch_bounds__(512) void finalize3_kernel(const float* __restrict__ part,
                                                        const float* __restrict__ w3T,
                                                        const float* __restrict__ g2,
                                                        const float* __restrict__ bt2,
                                                        float* __restrict__ w3S,
                                                        float* __restrict__ c3)
{
    __shared__ double tot[1024];
    __shared__ float As[128];
    const int tid = threadIdx.x;
    double sa = 0.0, sb = 0.0;
    for (int blk = 0; blk < 512; ++blk) {
        sa += (double)part[(size_t)blk * 1024 + tid];
        sb += (double)part[(size_t)blk * 1024 + 512 + tid];
    }
    tot[tid] = sa; tot[512 + tid] = sb;
    __syncthreads();
    if (tid < 128) {
        double S = 0.0, Q = 0.0;
        if (tid < 64) {
            for (int g = 0; g < 4; ++g) { S += tot[g * 64 + tid]; Q += tot[256 + g * 64 + tid]; }
        } else {
            const int u = tid - 64;
            for (int g = 0; g < 4; ++g) { S += tot[512 + g * 64 + u]; Q += tot[768 + g * 64 + u]; }
        }
        const double mean = S / (double)MTOT;
        double var = Q / (double)MTOT - mean * mean;
        if (var < 0.0) var = 0.0;
        const double A = (double)g2[tid] / sqrt(var + 1e-5);
        As[tid] = (float)A;
        c3[tid] = (float)((double)bt2[tid] - A * mean);
    }
    __syncthreads();
    for (int i = tid; i < 8192; i += 512) w3S[i] = As[i & 127] * w3T[i];
}

// ---------------------------------------------------------------------------
// Chain kernel: lane owns one point; 64-channel register accumulator; weights
// via wave-uniform scalar loads; h staged in a SELF-OWNED LDS column (dynamic
// k index). Barriers only around the cross-thread stats reduce.
// PHASE 2 = stats of x2nb (raw w2T); PHASE 3 = stats of x3nb (folded L2,
// raw w3T, recomputes h1/h2 for the second half); PHASE 4 = final output.
// ---------------------------------------------------------------------------
template<int PHASE>
__global__ __launch_bounds__(256) void chain_kernel(
    const float* __restrict__ v,
    const float* __restrict__ w1S, const float* __restrict__ c1v,
    const float* __restrict__ w2x, const float* __restrict__ c2v,
    const float* __restrict__ w3x, const float* __restrict__ c3v,
    float* __restrict__ part, float* __restrict__ outF, int tpb)
{
    __shared__ float hs[64][256];   // [k][pt] — column tid is self-owned
    const int tid  = threadIdx.x;
    const int lane = tid & 63;
    const int wv   = tid >> 6;
    const int ro   = tid & 63;      // reduce: channel
    const int rg   = tid >> 6;      // reduce: 64-pt group

    float sA = 0.f, qA = 0.f, sB = 0.f, qB = 0.f;

    for (int ti = 0; ti < tpb; ++ti) {
        const int tile = blockIdx.x * tpb + ti;
        const int m = tile * 256 + tid;
        float acc[64];

        auto compute_h1 = [&]() {
#pragma unroll
            for (int o = 0; o < 64; ++o) acc[o] = c1v[o];
            for (int c = 0; c < 6; ++c) {
                const float x = v[(size_t)c * MTOT + m];
                const float* __restrict__ wr = w1S + c * 64;
#pragma unroll
                for (int o = 0; o < 64; ++o) acc[o] = fmaf(wr[o], x, acc[o]);
            }
#pragma unroll
            for (int o = 0; o < 64; ++o) hs[o][tid] = fmaxf(acc[o], 0.f);
        };
        auto l2_loop = [&]() {
#pragma unroll
            for (int o = 0; o < 64; ++o) acc[o] = (PHASE == 2) ? 0.f : c2v[o];
            for (int k = 0; k < 64; ++k) {
                const float h = hs[k][tid];
                const float* __restrict__ wr = w2x + (k << 6);
#pragma unroll
                for (int o = 0; o < 64; ++o) acc[o] = fmaf(wr[o], h, acc[o]);
            }
        };
        auto l3_loop = [&](int half) {
#pragma unroll
            for (int o = 0; o < 64; ++o) acc[o] = (PHASE == 3) ? 0.f : c3v[(half << 6) + o];
            for (int k = 0; k < 64; ++k) {
                const float h = hs[k][tid];
                const float* __restrict__ wr = w3x + (k << 7) + (half << 6);
#pragma unroll
                for (int o = 0; o < 64; ++o) acc[o] = fmaf(wr[o], h, acc[o]);
            }
        };
        auto stats_reduce = [&](float& sOut, float& qOut) {
            // acc -> hs (raw), cross-thread reduce
            __syncthreads();
#pragma unroll
            for (int o = 0; o < 64; ++o) hs[o][tid] = acc[o];
            __syncthreads();
            float s = 0.f, q = 0.f;
            for (int j = 0; j < 64; ++j) {
                const float x = hs[ro][(rg << 6) + ((j + tid) & 63)];
                s += x; q = fmaf(x, x, q);
            }
            sOut += s; qOut += q;
            __syncthreads();   // protect hs before next overwrite
        };

        compute_h1();
        l2_loop();

        if constexpr (PHASE == 2) {
            stats_reduce(sA, qA);
        } else {
            // h2 -> hs
#pragma unroll
            for (int o = 0; o < 64; ++o) hs[o][tid] = fmaxf(acc[o], 0.f);
            l3_loop(0);
            if constexpr (PHASE == 3) {
                stats_reduce(sA, qA);
                // recompute h1, h2 (hs was clobbered by stats staging)
                compute_h1();
                l2_loop();
#pragma unroll
                for (int o = 0; o < 64; ++o) hs[o][tid] = fmaxf(acc[o], 0.f);
                l3_loop(1);
                stats_reduce(sB, qB);
            } else {
                // PHASE 4: y = relu(acc); group-max over 32 lanes; store
#pragma unroll
                for (int half = 0; half < 2; ++half) {
                    if (half == 1) l3_loop(1);
#pragma unroll
                    for (int o = 0; o < 64; ++o) acc[o] = fmaxf(acc[o], 0.f);
#pragma unroll
                    for (int off = 1; off < 32; off <<= 1) {
#pragma unroll
                        for (int o = 0; o < 64; ++o)
                            acc[o] = fmaxf(acc[o], __shfl_xor(acc[o], off));
                    }
                    if ((lane & 31) == 0) {
                        const int g = tile * 8 + wv * 2 + (lane >> 5);
#pragma unroll
                        for (int og = 0; og < 16; ++og) {
                            f4 t4;
                            t4.v[0] = acc[og * 4 + 0];
                            t4.v[1] = acc[og * 4 + 1];
                            t4.v[2] = acc[og * 4 + 2];
                            t4.v[3] = acc[og * 4 + 3];
                            *reinterpret_cast<f4*>(&outF[(size_t)g * 128 + (half << 6) + og * 4]) = t4;
                        }
                    }
                }
            }
        }
    }

    if constexpr (PHASE == 2) {
        part[(size_t)blockIdx.x * 512 + tid]       = sA;
        part[(size_t)blockIdx.x * 512 + 256 + tid] = qA;
    } else if constexpr (PHASE == 3) {
        part[(size_t)blockIdx.x * 1024 + tid]        = sA;
        part[(size_t)blockIdx.x * 1024 + 256 + tid]  = qA;
        part[(size_t)blockIdx.x * 1024 + 512 + tid]  = sB;
        part[(size_t)blockIdx.x * 1024 + 768 + tid]  = qB;
    }
}

// ---------------------------------------------------------------------------
extern "C" void kernel_launch(void* const* d_in, const int* in_sizes, int n_in,
                              void* d_out, int out_size, void* d_ws, size_t ws_size,
                              hipStream_t stream)
{
    const float* xyz  = (const float*)d_in[0];
    const float* feat = (const float*)d_in[1];
    const float* w0  = (const float*)d_in[2];
    const float* g0  = (const float*)d_in[4];
    const float* bt0 = (const float*)d_in[5];
    const float* w1  = (const float*)d_in[6];
    const float* g1  = (const float*)d_in[8];
    const float* bt1 = (const float*)d_in[9];
    const float* w2  = (const float*)d_in[10];
    const float* g2  = (const float*)d_in[12];
    const float* bt2 = (const float*)d_in[13];

    float* out    = (float*)d_out;
    float* newxyz = out;                 // (16,1024,3)
    float* outF   = out + BB * SS * 3;   // (16,1024,128)

    float* wsf  = (float*)d_ws;
    float* v    = wsf;                         // 6*MTOT
    float* part = wsf + 6ull * MTOT;           // max(16384*42, 512*1024) = 688128
    float* w2T  = part + 688128;               // 4096
    float* w3T  = w2T + 4096;                  // 8192
    float* w1S  = w3T + 8192;                  // 384
    float* w2S  = w1S + 384;                   // 4096
    float* w3S  = w2S + 4096;                  // 8192
    float* c1   = w3S + 8192;                  // 64
    float* c2   = c1 + 64;                     // 64
    float* c3   = c2 + 64;                     // 128

    prep_kernel<<<dim3(1), dim3(512), 0, stream>>>(w1, w2, w2T, w3T);
    fps_kernel<<<dim3(BB), dim3(512), 0, stream>>>(xyz, newxyz);
    ball_gather_kernel<<<dim3(4096), dim3(256), 0, stream>>>(xyz, feat, newxyz, v, part);
    finalize1_kernel<<<dim3(1), dim3(512), 0, stream>>>(part, w0, g0, bt0, w1S, c1);

    chain_kernel<2><<<dim3(512), dim3(256), 0, stream>>>(v, w1S, c1, w2T, nullptr,
                                                         nullptr, nullptr, part, nullptr, 4);
    finalize2_kernel<<<dim3(1), dim3(512), 0, stream>>>(part, w2T, g1, bt1, w2S, c2);

    chain_kernel<3><<<dim3(512), dim3(256), 0, stream>>>(v, w1S, c1, w2S, c2,
                                                         w3T, nullptr, part, nullptr, 4);
    finalize3_kernel<<<dim3(1), dim3(512), 0, stream>>>(part, w3T, g2, bt2, w3S, c3);

    chain_kernel<4><<<dim3(512), dim3(256), 0, stream>>>(v, w1S, c1, w2S, c2,
                                                         w3S, c3, nullptr, outF, 4);
}